// Round 4
// baseline (80.734 us; speedup 1.0000x reference)
//
#include <hip/hip_runtime.h>
#include <stdint.h>

#define HW 4096
#define NC 128
#define BATCH 2

typedef __attribute__((ext_vector_type(8))) short bf16x8;
typedef __attribute__((ext_vector_type(4))) float f32x4;
typedef __attribute__((ext_vector_type(8))) unsigned short u16x8;

__device__ __forceinline__ unsigned short f32_to_bf16(float f) {
    union { float f; unsigned int u; } v; v.f = f;
    unsigned int u = v.u;
    unsigned int r = (u + 0x7FFFu + ((u >> 16) & 1u)) >> 16;
    return (unsigned short)r;
}

// Async global->LDS, 16B/lane. LDS dest = wave-uniform base + lane*16 (m104).
__device__ __forceinline__ void async_cp16(const void* g, void* s) {
    __builtin_amdgcn_global_load_lds(
        (const __attribute__((address_space(1))) uint32_t*)g,
        (__attribute__((address_space(3))) uint32_t*)s, 16, 0, 0);
}

// L1-normalize + transpose to [b][pos][c] bf16, 16B-chunk swizzle
// slot = chunk ^ (pos&15) baked into the global layout. float2 loads along
// the position axis: each thread owns 2 positions x 8 channels.
__global__ __launch_bounds__(256) void norm_kernel(
    const float* __restrict__ A, const float* __restrict__ B,
    const float* __restrict__ Cc,
    unsigned short* __restrict__ anT, unsigned short* __restrict__ dT,
    float* __restrict__ out) {
    const int tid = threadIdx.x;
    if (blockIdx.x == 0 && tid == 0) *out = 0.f;  // replaces memset dispatch
    const int pl = tid & 15;            // 16 lanes x 2 positions = 32 pos/block
    const int cg = tid >> 4;            // channel group 0..15 (8 ch each)
    const int gp = blockIdx.x * 32;     // 256 blocks
    const int bb = gp >> 12;
    const int p0 = (gp & (HW - 1)) + pl * 2;
    const size_t base = (size_t)bb * NC * HW + p0;  // + c*HW -> x[b][c][p0]
    const int c0 = cg * 8;

    float2 va[8], vb[8], vc[8];
    float sa0 = 0.f, sa1 = 0.f, sb0 = 0.f, sb1 = 0.f, sc0 = 0.f, sc1 = 0.f;
#pragma unroll
    for (int k = 0; k < 8; ++k) {
        size_t idx = base + (size_t)(c0 + k) * HW;
        va[k] = *(const float2*)(A + idx);
        vb[k] = *(const float2*)(B + idx);
        vc[k] = *(const float2*)(Cc + idx);
        sa0 += fabsf(va[k].x); sa1 += fabsf(va[k].y);
        sb0 += fabsf(vb[k].x); sb1 += fabsf(vb[k].y);
        sc0 += fabsf(vc[k].x); sc1 += fabsf(vc[k].y);
    }
    __shared__ float red[3][16][32];
    red[0][cg][pl * 2] = sa0; red[0][cg][pl * 2 + 1] = sa1;
    red[1][cg][pl * 2] = sb0; red[1][cg][pl * 2 + 1] = sb1;
    red[2][cg][pl * 2] = sc0; red[2][cg][pl * 2 + 1] = sc1;
    __syncthreads();
    float na0 = 0.f, na1 = 0.f, nb0 = 0.f, nb1 = 0.f, nc0 = 0.f, nc1 = 0.f;
#pragma unroll
    for (int g = 0; g < 16; ++g) {
        na0 += red[0][g][pl * 2]; na1 += red[0][g][pl * 2 + 1];
        nb0 += red[1][g][pl * 2]; nb1 += red[1][g][pl * 2 + 1];
        nc0 += red[2][g][pl * 2]; nc1 += red[2][g][pl * 2 + 1];
    }
    const float ra0 = 1.f / fmaxf(na0, 1e-12f), ra1 = 1.f / fmaxf(na1, 1e-12f);
    const float rb0 = 1.f / fmaxf(nb0, 1e-12f), rb1 = 1.f / fmaxf(nb1, 1e-12f);
    const float rc0 = 1.f / fmaxf(nc0, 1e-12f), rc1 = 1.f / fmaxf(nc1, 1e-12f);

    const size_t ob0 = ((size_t)bb * HW + p0) * NC;
    const size_t ob1 = ob0 + NC;
    const int sl0 = cg ^ (p0 & 15);
    const int sl1 = cg ^ ((p0 + 1) & 15);
    u16x8 xa0, xa1, xd0, xd1;
#pragma unroll
    for (int j = 0; j < 8; ++j) {
        xa0[j] = f32_to_bf16(va[j].x * ra0);
        xa1[j] = f32_to_bf16(va[j].y * ra1);
        xd0[j] = f32_to_bf16(vc[j].x * rc0 - vb[j].x * rb0);
        xd1[j] = f32_to_bf16(vc[j].y * rc1 - vb[j].y * rb1);
    }
    *(u16x8*)(anT + ob0 + sl0 * 8) = xa0;
    *(u16x8*)(anT + ob1 + sl1 * 8) = xa1;
    *(u16x8*)(dT  + ob0 + sl0 * 8) = xd0;
    *(u16x8*)(dT  + ob1 + sl1 * 8) = xd1;
}

// Persistent-block GEMM, A fragments hoisted to registers (64 VGPR/wave),
// B double-buffered in LDS: fill of tile j+1 issued before compute of tile j,
// so the barrier vmcnt drain is hidden behind a full tile of MFMA.
// One 128x128 tile of S = A_n^T * D per (block, j); abs-sum -> one atomicAdd.
__global__ __launch_bounds__(256, 2) void simloss_kernel(
    const unsigned short* __restrict__ anT, const unsigned short* __restrict__ dT,
    float* __restrict__ out) {
    __shared__ uint4 smem4[4096];  // buf0 = [0,2048) 32KB, buf1 = [2048,4096)
    const int tid = threadIdx.x;
    const int b   = blockIdx.x;          // 0..511
    const int bz  = b >> 8;              // batch
    const int my  = (b & 255) >> 3;      // m-tile 0..31
    const int ng  = b & 7;               // n-group: tiles ng*4 .. ng*4+3
    const char* gA  = (const char*)(anT + ((size_t)bz * HW + my * 128) * NC);
    const char* gB0 = (const char*)(dT + ((size_t)bz * HW + ng * 4 * 128) * NC);

    const int wv = tid >> 6;
    const int ln = tid & 63;
    char* buf0 = (char*)smem4;
    char* buf1 = (char*)(smem4 + 2048);

    // Stage A -> buf0, B0 -> buf1 (8 x 16B per thread each, async).
#pragma unroll
    for (int i = 0; i < 8; ++i) {
        const size_t goff = (size_t)(i * 256 + tid) * 16;
        const size_t loff = (size_t)i * 4096 + wv * 1024;  // wave-uniform base
        async_cp16(gA + goff, buf0 + loff);
        async_cp16(gB0 + goff, buf1 + loff);
    }
    __syncthreads();

    const int m16  = ln & 15;
    const int quad = ln >> 4;
    const int wr   = (wv >> 1) * 64;
    const int wc   = (wv & 1) * 64;

    // Hoist this wave's A fragments into registers: 16 x bf16x8 = 64 VGPRs.
    bf16x8 aF[4][4];  // [mi][ks]
#pragma unroll
    for (int ks = 0; ks < 4; ++ks) {
        const int slot = (ks * 4 + quad) ^ m16;
#pragma unroll
        for (int mi = 0; mi < 4; ++mi)
            aF[mi][ks] = *(const bf16x8*)(buf0 + (wr + mi * 16 + m16) * 256 + slot * 16);
    }
    __syncthreads();  // all waves done with A region; buf0 becomes B staging

    // Prefetch B1 -> buf0.
#pragma unroll
    for (int i = 0; i < 8; ++i)
        async_cp16(gB0 + 32768 + (size_t)(i * 256 + tid) * 16,
                   buf0 + (size_t)i * 4096 + wv * 1024);

    float s = 0.f;
    for (int j = 0; j < 4; ++j) {
        if (j) {
            __syncthreads();             // drains fill of B_j; frees prev buffer
            if (j < 3) {                 // prefetch B_{j+1} into the freed buffer
                char* dst = (j & 1) ? buf1 : buf0;
                const char* src = gB0 + (size_t)(j + 1) * 32768;
#pragma unroll
                for (int i = 0; i < 8; ++i)
                    async_cp16(src + (size_t)(i * 256 + tid) * 16,
                               dst + (size_t)i * 4096 + wv * 1024);
            }
        }
        const char* sB = (j & 1) ? buf0 : buf1;
        f32x4 acc[4][4] = {};
#pragma unroll
        for (int ks = 0; ks < 4; ++ks) {
            const int slot = (ks * 4 + quad) ^ m16;
            bf16x8 bfr[4];
#pragma unroll
            for (int ni = 0; ni < 4; ++ni)
                bfr[ni] = *(const bf16x8*)(sB + (wc + ni * 16 + m16) * 256 + slot * 16);
#pragma unroll
            for (int mi = 0; mi < 4; ++mi)
#pragma unroll
                for (int ni = 0; ni < 4; ++ni)
                    acc[mi][ni] = __builtin_amdgcn_mfma_f32_16x16x32_bf16(
                        aF[mi][ks], bfr[ni], acc[mi][ni], 0, 0, 0);
        }
#pragma unroll
        for (int mi = 0; mi < 4; ++mi)
#pragma unroll
            for (int ni = 0; ni < 4; ++ni)
#pragma unroll
                for (int r = 0; r < 4; ++r)
                    s += fabsf(acc[mi][ni][r]);
    }

#pragma unroll
    for (int off = 32; off > 0; off >>= 1)
        s += __shfl_down(s, off);
    __syncthreads();
    if (ln == 0) ((float*)smem4)[wv] = s;
    __syncthreads();
    if (tid == 0) {
        const float inv = 1.0f / ((float)BATCH * (float)HW * (float)HW);
        float t = ((float*)smem4)[0] + ((float*)smem4)[1] +
                  ((float*)smem4)[2] + ((float*)smem4)[3];
        atomicAdd(out, t * inv);
    }
}

extern "C" void kernel_launch(void* const* d_in, const int* in_sizes, int n_in,
                              void* d_out, int out_size, void* d_ws, size_t ws_size,
                              hipStream_t stream) {
    const float* A  = (const float*)d_in[0];
    const float* B  = (const float*)d_in[1];
    const float* Cc = (const float*)d_in[2];
    float* out = (float*)d_out;
    unsigned short* anT = (unsigned short*)d_ws;                 // 2 MB
    unsigned short* dT  = anT + (size_t)BATCH * HW * NC;         // 2 MB

    norm_kernel<<<dim3(256), dim3(256), 0, stream>>>(A, B, Cc, anT, dT, out);
    simloss_kernel<<<dim3(512), dim3(256), 0, stream>>>(anT, dT, out);
}